// Round 12
// baseline (395.782 us; speedup 1.0000x reference)
//
#include <hip/hip_runtime.h>
#include <hip/hip_bf16.h>

#define NN 4096
#define FF 512
#define NH 8
#define DH 64

typedef __attribute__((ext_vector_type(8))) short bf16x8;
typedef __attribute__((ext_vector_type(4))) float f32x4;

// ws layout in ushort elements:
//  X_BF  [4096][512]                    @ 0
//  W_BF  [3][512][512]                  @ 2097152   (Wq pre-scaled by 1/sqrt(512))
//  QF    [8][256 blk][2 half][64 ln][8] @ 2883584   (MFMA A-fragment order)
//  KF    [8][256 blk][2 half][64 ln][8] @ 4980736   (MFMA B-fragment order)
//  VF    [8][64 kb][4 dt][2 hf][64][8]  @ 7077888   (MFMA B-fragment order, d-major)
//  PACC  bf16 [4 ks][8 h][4096][64]     @ 9175040   (8388608 ushorts)
//  PDEN  f32  [4 ks][8 h][4096]         @ 17563648  (262144 ushorts)
#define X_OFF  0
#define W_OFF  2097152
#define QF_OFF 2883584
#define KF_OFF 4980736
#define VF_OFF 7077888
#define PACC_OFF 9175040
#define PDEN_USHORT_OFF 17563648

__device__ __forceinline__ ushort f2bf(float f) {
    __hip_bfloat16 h = __float2bfloat16(f);
    return __builtin_bit_cast(ushort, h);
}
__device__ __forceinline__ float bf2f(ushort u) {
    unsigned int v = ((unsigned int)u) << 16;
    return __builtin_bit_cast(float, v);
}

// ---------------- kernel 0: f32 -> bf16 convert (x, Wq*scale, Wk, Wv) ----------------
__global__ __launch_bounds__(256) void cvt_kernel(const float* __restrict__ x,
                                                  const float* __restrict__ wq,
                                                  const float* __restrict__ wk,
                                                  const float* __restrict__ wv,
                                                  ushort* __restrict__ ws) {
    int i = blockIdx.x * 256 + threadIdx.x;
    int base = i * 4;
    const float* src;
    int off;
    float sc = 1.f;
    if (base < 2097152) { src = x; off = base; }
    else {
        int t = base - 2097152;
        int m = t >> 18;
        src = (m == 0) ? wq : ((m == 1) ? wk : wv);
        if (m == 0) sc = 0.044194173824159216f;   // 1/sqrt(512) folded into Wq
        off = t & 262143;
    }
    float4 v = *reinterpret_cast<const float4*>(src + off);
    ushort4 o;
    o.x = f2bf(v.x * sc); o.y = f2bf(v.y * sc); o.z = f2bf(v.z * sc); o.w = f2bf(v.w * sc);
    *reinterpret_cast<ushort4*>(ws + base) = o;
}

// ---------------- kernel 1: QKV projection, outputs in MFMA-fragment order ----------------
__global__ __launch_bounds__(256) void qkv_kernel(ushort* __restrict__ ws) {
    int bx = blockIdx.x;
    int mat = bx >> 3;          // 0=Q,1=K,2=V
    int fb  = bx & 7;           // head
    int mb  = blockIdx.y;
    int wave = threadIdx.x >> 6, lane = threadIdx.x & 63;
    int la = lane & 15, lk = lane >> 4;

    int m_base = mb * 64 + wave * 16;
    int f_base = fb * 64;

    const ushort* xb = ws + X_OFF;
    const ushort* wb = ws + W_OFF + mat * 262144;

    f32x4 acc[4];
#pragma unroll
    for (int t = 0; t < 4; ++t) acc[t] = (f32x4){0.f, 0.f, 0.f, 0.f};

#pragma unroll 4
    for (int k0 = 0; k0 < 512; k0 += 32) {
        bf16x8 a = *reinterpret_cast<const bf16x8*>(xb + (size_t)(m_base + la) * 512 + k0 + lk * 8);
#pragma unroll
        for (int ft = 0; ft < 4; ++ft) {
            bf16x8 b = *reinterpret_cast<const bf16x8*>(wb + (size_t)(f_base + ft * 16 + la) * 512 + k0 + lk * 8);
            acc[ft] = __builtin_amdgcn_mfma_f32_16x16x32_bf16(a, b, acc[ft], 0, 0, 0);
        }
    }

#pragma unroll
    for (int ft = 0; ft < 4; ++ft) {
#pragma unroll
        for (int r = 0; r < 4; ++r) {
            int n = m_base + lk * 4 + r;
            int d = ft * 16 + la;          // head-local feature
            ushort v = f2bf(acc[ft][r]);
            if (mat < 2) {
                ushort* base = ws + (mat == 0 ? QF_OFF : KF_OFF) + (size_t)fb * 262144;
                int blk = n >> 4, rr = n & 15;
                int half = d >> 5, lkk = (d >> 3) & 3, e = d & 7;
                base[(((size_t)blk * 2 + half) * 64 + lkk * 16 + rr) * 8 + e] = v;
            } else {
                ushort* base = ws + VF_OFF + (size_t)fb * 262144;
                int kb64 = n >> 6, kc = n & 63;
                int hf = kc >> 5, lkv = (kc >> 3) & 3, ev = kc & 7;
                int dt = d >> 4, lav = d & 15;
                base[((((size_t)kb64 * 4 + dt) * 2 + hf) * 64 + lkv * 16 + lav) * 8 + ev] = v;
            }
        }
    }
}

// ---------------- kernel 2: masked attention, contiguous-ballot adj, R9 schedule -------
// grid 2048: h = bid&7 (XCD-pinned), qb = (bid>>3)&63, ks = bid>>9 (0..3).
// 4 waves x 16 q-rows; 16 bodies of 64 keys (1024 keys/block).
// adj ingestion in PACK's shape: per body, 16 loads, each = ONE contiguous 256B row
// chunk (lane l <-> key l), __ballot -> 64-bit row masks in SGPRs (bit l = key l).
// Counted vmcnt: body-top vmcnt(16) drains exactly stage(t); the 16 adj loads for
// body t+1 stay in flight across the barrier; ballot at body end (~1.5-body-old loads).

#define STAGE(BUF, KB)                                                                     \
    {                                                                                      \
        const ushort* sbase_ = (wave < 2) ? Kh : Vh;                                       \
        ushort(*dbuf_)[512] = (wave < 2) ? kbuf[BUF] : vbuf[BUF];                          \
        int t0_ = (wave & 1) * 4;                                                          \
        _Pragma("unroll")                                                                  \
        for (int t_ = 0; t_ < 4; ++t_) {                                                   \
            int tile_ = t0_ + t_;                                                          \
            const ushort* src_ = sbase_ +                                                  \
                (((size_t)(KB) * 4 + (tile_ >> 1)) * 2 + (tile_ & 1)) * 512 + lane * 8;    \
            __builtin_amdgcn_global_load_lds(                                              \
                (const __attribute__((address_space(1))) unsigned int*)src_,               \
                (__attribute__((address_space(3))) unsigned int*)&dbuf_[tile_][0],         \
                16, 0, 0);                                                                 \
        }                                                                                  \
    }

// contiguous adj loads: row j of this wave, keys kb*64 .. +63, lane l <-> key l
#define ADJ_LOAD(KB)                                                                       \
    {                                                                                      \
        _Pragma("unroll")                                                                  \
        for (int j_ = 0; j_ < 16; ++j_)                                                    \
            adjv[j_] = __builtin_nontemporal_load(                                         \
                adjw + (size_t)j_ * 4096 + (size_t)(KB) * 64 + lane);                      \
    }

#define ADJ_BALLOT()                                                                       \
    {                                                                                      \
        _Pragma("unroll")                                                                  \
        for (int j_ = 0; j_ < 16; ++j_)                                                    \
            m[j_] = __ballot(adjv[j_] != 0);                                               \
    }

// one attention body: masks from SGPR m[], K/V from LDS buffers (parity CUR)
#define COMPUTE(CUR)                                                                       \
    {                                                                                      \
        unsigned int mlo[4], mhi[4];                                                       \
        _Pragma("unroll")                                                                  \
        for (int r = 0; r < 4; ++r) {                                                      \
            unsigned long long a_ = (lk & 1) ? m[4 + r] : m[r];                            \
            unsigned long long b_ = (lk & 1) ? m[12 + r] : m[8 + r];                       \
            unsigned long long sel_ = (lk & 2) ? b_ : a_;                                  \
            mlo[r] = (unsigned int)sel_;                                                   \
            mhi[r] = (unsigned int)(sel_ >> 32);                                           \
        }                                                                                  \
        _Pragma("unroll")                                                                  \
        for (int kt = 0; kt < 4; ++kt) {                                                   \
            bf16x8 kf0 = *reinterpret_cast<const bf16x8*>(&kbuf[CUR][kt * 2 + 0][lane * 8]); \
            bf16x8 kf1 = *reinterpret_cast<const bf16x8*>(&kbuf[CUR][kt * 2 + 1][lane * 8]); \
            f32x4 s = __builtin_amdgcn_mfma_f32_16x16x32_bf16(qa0, kf0, zero, 0, 0, 0);    \
            s = __builtin_amdgcn_mfma_f32_16x16x32_bf16(qa1, kf1, s, 0, 0, 0);             \
            int sh_ = la + ((kt & 1) << 4);                                                \
            _Pragma("unroll")                                                              \
            for (int r = 0; r < 4; ++r) {                                                  \
                unsigned int dw_ = (kt < 2) ? mlo[r] : mhi[r];                             \
                float sv = ((dw_ >> sh_) & 1u) ? s[r] : -1e30f;                            \
                float e = __expf(sv);                                                      \
                den[r] += e;                                                               \
                P[wave][lk * 4 + r][kt * 16 + la] = f2bf(e);                               \
            }                                                                              \
        }                                                                                  \
        bf16x8 pa0 = *reinterpret_cast<const bf16x8*>(&P[wave][la][lk * 8]);               \
        bf16x8 pa1 = *reinterpret_cast<const bf16x8*>(&P[wave][la][32 + lk * 8]);          \
        _Pragma("unroll")                                                                  \
        for (int dt = 0; dt < 4; ++dt) {                                                   \
            bf16x8 vb0 = *reinterpret_cast<const bf16x8*>(&vbuf[CUR][dt * 2 + 0][lane * 8]); \
            bf16x8 vb1 = *reinterpret_cast<const bf16x8*>(&vbuf[CUR][dt * 2 + 1][lane * 8]); \
            acc[dt] = __builtin_amdgcn_mfma_f32_16x16x32_bf16(pa0, vb0, acc[dt], 0, 0, 0); \
            acc[dt] = __builtin_amdgcn_mfma_f32_16x16x32_bf16(pa1, vb1, acc[dt], 0, 0, 0); \
        }                                                                                  \
    }

__global__ __launch_bounds__(256, 3) void attn_kernel(const int* __restrict__ adj,
                                                      const ushort* __restrict__ ws,
                                                      ushort* __restrict__ pacc,
                                                      float* __restrict__ pden) {
    __shared__ ushort kbuf[2][8][512];   // 16KB
    __shared__ ushort vbuf[2][8][512];   // 16KB
    __shared__ ushort P[4][16][72];      // 9.2KB per-wave P staging (72 = pad, 2-way banks)

    int bid = blockIdx.x;
    int h = bid & 7, qb = (bid >> 3) & 63, ks = bid >> 9;
    int wave = threadIdx.x >> 6, lane = threadIdx.x & 63;
    int la = lane & 15, lk = lane >> 4;
    int q0w = qb * 64 + wave * 16;

    const ushort* Qh = ws + QF_OFF + (size_t)h * 262144;
    const ushort* Kh = ws + KF_OFF + (size_t)h * 262144;
    const ushort* Vh = ws + VF_OFF + (size_t)h * 262144;
    const int* adjw = adj + (size_t)h * 16777216 + (size_t)q0w * 4096;

    bf16x8 qa0 = *reinterpret_cast<const bf16x8*>(Qh + ((((size_t)(q0w >> 4)) * 2 + 0) * 64 + lane) * 8);
    bf16x8 qa1 = *reinterpret_cast<const bf16x8*>(Qh + ((((size_t)(q0w >> 4)) * 2 + 1) * 64 + lane) * 8);

    f32x4 acc[4];
    float den[4];
#pragma unroll
    for (int r = 0; r < 4; ++r) {
        acc[r] = (f32x4){0.f, 0.f, 0.f, 0.f};
        den[r] = 0.f;
    }

    const f32x4 zero = {0.f, 0.f, 0.f, 0.f};
    int kbase = ks * 16;   // bodies kbase .. kbase+15 (64 keys each)

    int adjv[16];
    unsigned long long m[16];   // wave-uniform row masks (SGPR pairs), bit l = key l

    // prologue: FIFO = [stage(0)4, adj(0)16, adj(1)16]; vmcnt(16) drains stage(0)+adj(0)
    STAGE(0, kbase)
    __builtin_amdgcn_sched_barrier(0);
    ADJ_LOAD(kbase)
    __builtin_amdgcn_sched_barrier(0);
    int adjB[16];
#pragma unroll
    for (int j = 0; j < 16; ++j)
        adjB[j] = __builtin_nontemporal_load(adjw + (size_t)j * 4096 + (size_t)(kbase + 1) * 64 + lane);
    __builtin_amdgcn_sched_barrier(0);
    asm volatile("s_waitcnt vmcnt(16)" ::: "memory");
    ADJ_BALLOT()              // masks for body 0 (from adjv)
#pragma unroll
    for (int j = 0; j < 16; ++j) adjv[j] = adjB[j];   // adjv now holds body-1 raw
    __builtin_amdgcn_s_barrier();

    // steady bodies 0..13: stage(t+1), adjload(t+2), compute(t), ballot(t+1)
    for (int it = 0; it < 14; ++it) {
        int kb = kbase + it;
        int cur = it & 1;
        asm volatile("s_waitcnt vmcnt(16)" ::: "memory");   // drains stage(t); adj(t+1) stays
        __builtin_amdgcn_s_barrier();
        STAGE(cur ^ 1, kb + 1)
        __builtin_amdgcn_sched_barrier(0);
        int adjN[16];
#pragma unroll
        for (int j = 0; j < 16; ++j)
            adjN[j] = __builtin_nontemporal_load(adjw + (size_t)j * 4096 + (size_t)(kb + 2) * 64 + lane);
        __builtin_amdgcn_sched_barrier(0);
        COMPUTE(cur)
        __builtin_amdgcn_sched_barrier(0);
        ADJ_BALLOT()          // body t+1 masks (adjv loads ~1.5 bodies old)
#pragma unroll
        for (int j = 0; j < 16; ++j) adjv[j] = adjN[j];
    }

    // body 14: stage(15), no new adj, ballot(15)
    {
        asm volatile("s_waitcnt vmcnt(16)" ::: "memory");
        __builtin_amdgcn_s_barrier();
        STAGE(1, kbase + 15)   // body 15 parity = 15&1 = 1
        __builtin_amdgcn_sched_barrier(0);
        COMPUTE(0)             // body 14 parity 0
        __builtin_amdgcn_sched_barrier(0);
        ADJ_BALLOT()
    }
    // body 15: drain all, compute
    {
        asm volatile("s_waitcnt vmcnt(0)" ::: "memory");
        __builtin_amdgcn_s_barrier();
        COMPUTE(1)
    }

    // reduce den over the 16-lane key dimension
#pragma unroll
    for (int r = 0; r < 4; ++r)
#pragma unroll
        for (int mm = 1; mm < 16; mm <<= 1)
            den[r] += __shfl_xor(den[r], mm, 64);

    // store bf16 partial acc + f32 partial den
    ushort* pa_out = pacc + ((size_t)ks * 8 + h) * 4096 * 64;
#pragma unroll
    for (int dt = 0; dt < 4; ++dt)
#pragma unroll
        for (int r = 0; r < 4; ++r) {
            int q = q0w + lk * 4 + r;
            __builtin_nontemporal_store(f2bf(acc[dt][r]), pa_out + (size_t)q * 64 + dt * 16 + la);
        }
    if (la == 0) {
        float* pd = pden + ((size_t)ks * 8 + h) * 4096;
#pragma unroll
        for (int r = 0; r < 4; ++r)
            pd[q0w + lk * 4 + r] = den[r];
    }
}

// ---------------- kernel 3: combine bf16 partials + epilogue ----------------
__global__ __launch_bounds__(256) void combine_kernel(const float* __restrict__ x,
                                                      const ushort* __restrict__ pacc,
                                                      const float* __restrict__ pden,
                                                      float* __restrict__ out) {
    int idx = blockIdx.x * 256 + threadIdx.x;   // 524288 total
    int n = idx >> 7, fq = idx & 127;
    int h = fq >> 4;
    int d4 = (fq & 15) * 4;

    float4 o = make_float4(0.f, 0.f, 0.f, 0.f);
    float den = 0.f;
#pragma unroll
    for (int ksp = 0; ksp < 4; ++ksp) {
        const ushort* pa = pacc + (((size_t)ksp * 8 + h) * 4096 + n) * 64 + d4;
        ushort4 p = *reinterpret_cast<const ushort4*>(pa);
        o.x += bf2f(p.x); o.y += bf2f(p.y); o.z += bf2f(p.z); o.w += bf2f(p.w);
        den += pden[((size_t)ksp * 8 + h) * 4096 + n];
    }
    float4 xv = *reinterpret_cast<const float4*>(x + (size_t)n * 512 + fq * 4);
    float inv = 1.f / den;
    float4 r;
    r.x = o.x * inv + xv.x;
    r.y = o.y * inv + xv.y;
    r.z = o.z * inv + xv.z;
    r.w = o.w * inv + xv.w;
    r.x = (r.x > 0.f) ? r.x : (__expf(r.x) - 1.f);
    r.y = (r.y > 0.f) ? r.y : (__expf(r.y) - 1.f);
    r.z = (r.z > 0.f) ? r.z : (__expf(r.z) - 1.f);
    r.w = (r.w > 0.f) ? r.w : (__expf(r.w) - 1.f);
    *reinterpret_cast<float4*>(out + (size_t)n * 512 + fq * 4) = r;
}

extern "C" void kernel_launch(void* const* d_in, const int* in_sizes, int n_in,
                              void* d_out, int out_size, void* d_ws, size_t ws_size,
                              hipStream_t stream) {
    const float* x  = (const float*)d_in[0];
    const float* wq = (const float*)d_in[1];
    const float* wk = (const float*)d_in[2];
    const float* wv = (const float*)d_in[3];
    const int*   adj = (const int*)d_in[4];
    float* out = (float*)d_out;
    ushort* ws = (ushort*)d_ws;
    ushort* pacc = ws + PACC_OFF;
    float* pden = (float*)(ws + PDEN_USHORT_OFF);

    cvt_kernel<<<2816, 256, 0, stream>>>(x, wq, wk, wv, ws);
    qkv_kernel<<<dim3(24, 64), 256, 0, stream>>>(ws);
    attn_kernel<<<2048, 256, 0, stream>>>(adj, ws, pacc, pden);
    combine_kernel<<<2048, 256, 0, stream>>>(x, pacc, pden, out);
}

// Round 13
// 249.955 us; speedup vs baseline: 1.5834x; 1.5834x over previous
//
#include <hip/hip_runtime.h>
#include <hip/hip_bf16.h>

#define NN 4096
#define FF 512
#define NH 8
#define DH 64

typedef __attribute__((ext_vector_type(8))) short bf16x8;
typedef __attribute__((ext_vector_type(4))) float f32x4;

// ws layout in ushort elements:
//  X_BF  [4096][512]                    @ 0
//  W_BF  [3][512][512]                  @ 2097152   (Wq pre-scaled by 1/sqrt(512))
//  QF    [8][256 blk][2 half][64 ln][8] @ 2883584   (MFMA A-fragment order)
//  KF    [8][256 blk][2 half][64 ln][8] @ 4980736   (MFMA B-fragment order)
//  VF    [8][64 kb][4 dt][2 hf][64][8]  @ 7077888   (MFMA B-fragment order, d-major)
//  PACC  bf16 [4 ks][8 h][4096][64]     @ 9175040   (8388608 ushorts)
//  PDEN  f32  [4 ks][8 h][4096]         @ 17563648  (262144 ushorts)
//  PK    u32  [8*4096 rows][128]        @ 17825792  (8388608 ushorts; bit c of dword j
//                                                    = adj!=0 at col j*32+c)
#define X_OFF  0
#define W_OFF  2097152
#define QF_OFF 2883584
#define KF_OFF 4980736
#define VF_OFF 7077888
#define PACC_OFF 9175040
#define PDEN_USHORT_OFF 17563648
#define PK_USHORT_OFF 17825792

__device__ __forceinline__ ushort f2bf(float f) {
    __hip_bfloat16 h = __float2bfloat16(f);
    return __builtin_bit_cast(ushort, h);
}
__device__ __forceinline__ float bf2f(ushort u) {
    unsigned int v = ((unsigned int)u) << 16;
    return __builtin_bit_cast(float, v);
}

// ---------------- kernel 0: f32 -> bf16 convert (x, Wq*scale, Wk, Wv) ----------------
__global__ __launch_bounds__(256) void cvt_kernel(const float* __restrict__ x,
                                                  const float* __restrict__ wq,
                                                  const float* __restrict__ wk,
                                                  const float* __restrict__ wv,
                                                  ushort* __restrict__ ws) {
    int i = blockIdx.x * 256 + threadIdx.x;
    int base = i * 4;
    const float* src;
    int off;
    float sc = 1.f;
    if (base < 2097152) { src = x; off = base; }
    else {
        int t = base - 2097152;
        int m = t >> 18;
        src = (m == 0) ? wq : ((m == 1) ? wk : wv);
        if (m == 0) sc = 0.044194173824159216f;   // 1/sqrt(512) folded into Wq
        off = t & 262143;
    }
    float4 v = *reinterpret_cast<const float4*>(src + off);
    ushort4 o;
    o.x = f2bf(v.x * sc); o.y = f2bf(v.y * sc); o.z = f2bf(v.z * sc); o.w = f2bf(v.w * sc);
    *reinterpret_cast<ushort4*>(ws + base) = o;
}

// ---------------- kernel 1: pack (8192 blocks) || qkv (1536 blocks), one launch --------
// pack: proven-BW adj streamer. One wave per row, contiguous 256B/instr, __ballot 64:1.
// qkv: projections into MFMA-fragment order. Rides inside pack's memory time.
__global__ __launch_bounds__(256) void packqkv_kernel(const int* __restrict__ adj,
                                                      unsigned int* __restrict__ pk,
                                                      ushort* __restrict__ ws) {
    int bid = blockIdx.x;
    int wave = threadIdx.x >> 6, lane = threadIdx.x & 63;

    if (bid < 8192) {
        // ---- pack: row = h*4096+n, 64 chunks of 64 cols ----
        int row = bid * 4 + wave;
        const int* ar = adj + (size_t)row * 4096;
        unsigned long long* outp = reinterpret_cast<unsigned long long*>(pk + (size_t)row * 128);
        for (int it = 0; it < 64; it += 4) {
            int v0 = __builtin_nontemporal_load(ar + (it + 0) * 64 + lane);
            int v1 = __builtin_nontemporal_load(ar + (it + 1) * 64 + lane);
            int v2 = __builtin_nontemporal_load(ar + (it + 2) * 64 + lane);
            int v3 = __builtin_nontemporal_load(ar + (it + 3) * 64 + lane);
            unsigned long long b0 = __ballot(v0 != 0);
            unsigned long long b1 = __ballot(v1 != 0);
            unsigned long long b2 = __ballot(v2 != 0);
            unsigned long long b3 = __ballot(v3 != 0);
            if (lane == 0) {
                outp[it + 0] = b0;
                outp[it + 1] = b1;
                outp[it + 2] = b2;
                outp[it + 3] = b3;
            }
        }
        return;
    }

    // ---- qkv ----
    int q = bid - 8192;            // 0..1535
    int mat = q >> 9;              // 0=Q,1=K,2=V
    int rem = q & 511;
    int fb = rem & 7;              // head
    int mb = rem >> 3;             // 0..63
    int la = lane & 15, lk = lane >> 4;

    int m_base = mb * 64 + wave * 16;
    int f_base = fb * 64;

    const ushort* xb = ws + X_OFF;
    const ushort* wb = ws + W_OFF + mat * 262144;

    f32x4 acc[4];
#pragma unroll
    for (int t = 0; t < 4; ++t) acc[t] = (f32x4){0.f, 0.f, 0.f, 0.f};

#pragma unroll 4
    for (int k0 = 0; k0 < 512; k0 += 32) {
        bf16x8 a = *reinterpret_cast<const bf16x8*>(xb + (size_t)(m_base + la) * 512 + k0 + lk * 8);
#pragma unroll
        for (int ft = 0; ft < 4; ++ft) {
            bf16x8 b = *reinterpret_cast<const bf16x8*>(wb + (size_t)(f_base + ft * 16 + la) * 512 + k0 + lk * 8);
            acc[ft] = __builtin_amdgcn_mfma_f32_16x16x32_bf16(a, b, acc[ft], 0, 0, 0);
        }
    }

#pragma unroll
    for (int ft = 0; ft < 4; ++ft) {
#pragma unroll
        for (int r = 0; r < 4; ++r) {
            int n = m_base + lk * 4 + r;
            int d = ft * 16 + la;          // head-local feature
            ushort v = f2bf(acc[ft][r]);
            if (mat < 2) {
                ushort* base = ws + (mat == 0 ? QF_OFF : KF_OFF) + (size_t)fb * 262144;
                int blk = n >> 4, rr = n & 15;
                int half = d >> 5, lkk = (d >> 3) & 3, e = d & 7;
                base[(((size_t)blk * 2 + half) * 64 + lkk * 16 + rr) * 8 + e] = v;
            } else {
                ushort* base = ws + VF_OFF + (size_t)fb * 262144;
                int kb64 = n >> 6, kc = n & 63;
                int hf = kc >> 5, lkv = (kc >> 3) & 3, ev = kc & 7;
                int dt = d >> 4, lav = d & 15;
                base[((((size_t)kb64 * 4 + dt) * 2 + hf) * 64 + lkv * 16 + lav) * 8 + ev] = v;
            }
        }
    }
}

// ---------------- kernel 2: attention from bitmasks — barrier-free, L2-resident --------
// grid 2048: h = bid&7 (XCD-pinned: K/V 1MB + pk 2MB per head in that XCD's L2),
// qb = (bid>>3)&63, ks = bid>>9 (0..3). 4 waves x 16 q-rows; 16 bodies of 64 keys.
// NO __syncthreads, NO staging, NO inline vmcnt: pure TLP at 16 waves/CU (VGPR ~80).
// Main loop touches HBM zero times (masks + K/V + Q all L2-resident per XCD).
__global__ __launch_bounds__(256, 4) void attn_kernel(const unsigned int* __restrict__ pk,
                                                      const ushort* __restrict__ ws,
                                                      ushort* __restrict__ pacc,
                                                      float* __restrict__ pden) {
    __shared__ ushort P[4][16][72];   // per-wave P staging only (9.2KB)

    int bid = blockIdx.x;
    int h = bid & 7, qb = (bid >> 3) & 63, ks = bid >> 9;
    int wave = threadIdx.x >> 6, lane = threadIdx.x & 63;
    int la = lane & 15, lk = lane >> 4;
    int q0w = qb * 64 + wave * 16;

    const ushort* Qh = ws + QF_OFF + (size_t)h * 262144;
    const ushort* Kh = ws + KF_OFF + (size_t)h * 262144;
    const ushort* Vh = ws + VF_OFF + (size_t)h * 262144;
    const unsigned int* pkh = pk + (size_t)h * 4096 * 128;

    bf16x8 qa0 = *reinterpret_cast<const bf16x8*>(Qh + ((((size_t)(q0w >> 4)) * 2 + 0) * 64 + lane) * 8);
    bf16x8 qa1 = *reinterpret_cast<const bf16x8*>(Qh + ((((size_t)(q0w >> 4)) * 2 + 1) * 64 + lane) * 8);

    f32x4 acc[4];
    float den[4];
    int rowm[4];
#pragma unroll
    for (int r = 0; r < 4; ++r) {
        acc[r] = (f32x4){0.f, 0.f, 0.f, 0.f};
        den[r] = 0.f;
        rowm[r] = (q0w + lk * 4 + r) * 128;
    }

    const f32x4 zero = {0.f, 0.f, 0.f, 0.f};
    int kb0 = ks * 16;

    for (int it = 0; it < 16; ++it) {
        int kb = kb0 + it;

        // per-row 64-bit masks for this body (8B from L2, la-lanes broadcast)
        uint2 mk[4];
#pragma unroll
        for (int r = 0; r < 4; ++r)
            mk[r] = *reinterpret_cast<const uint2*>(pkh + rowm[r] + kb * 2);

        // QK^T from L2-resident fragment-order K
        f32x4 s[4];
#pragma unroll
        for (int kt = 0; kt < 4; ++kt) {
            const ushort* kp = Kh + (((size_t)(kb * 4 + kt) * 2) * 64 + lane) * 8;
            bf16x8 kf0 = *reinterpret_cast<const bf16x8*>(kp);
            bf16x8 kf1 = *reinterpret_cast<const bf16x8*>(kp + 512);
            s[kt] = __builtin_amdgcn_mfma_f32_16x16x32_bf16(qa0, kf0, zero, 0, 0, 0);
            s[kt] = __builtin_amdgcn_mfma_f32_16x16x32_bf16(qa1, kf1, s[kt], 0, 0, 0);
        }

        // mask + exp + P->LDS (bit (la + 16*(kt&1)) of dword kt>>1)
#pragma unroll
        for (int kt = 0; kt < 4; ++kt) {
            int sh = la + ((kt & 1) << 4);
#pragma unroll
            for (int r = 0; r < 4; ++r) {
                unsigned int dw = (kt < 2) ? mk[r].x : mk[r].y;
                float sv = ((dw >> sh) & 1u) ? s[kt][r] : -1e30f;
                float e = __expf(sv);
                den[r] += e;
                P[wave][lk * 4 + r][kt * 16 + la] = f2bf(e);
            }
        }

        // PV from L2-resident fragment-order V (P: same-wave write->read, lgkm ordered)
        bf16x8 pa0 = *reinterpret_cast<const bf16x8*>(&P[wave][la][lk * 8]);
        bf16x8 pa1 = *reinterpret_cast<const bf16x8*>(&P[wave][la][32 + lk * 8]);
#pragma unroll
        for (int dt = 0; dt < 4; ++dt) {
            const ushort* vp = Vh + ((((size_t)kb * 4 + dt) * 2) * 64 + lane) * 8;
            bf16x8 vb0 = *reinterpret_cast<const bf16x8*>(vp);
            bf16x8 vb1 = *reinterpret_cast<const bf16x8*>(vp + 512);
            acc[dt] = __builtin_amdgcn_mfma_f32_16x16x32_bf16(pa0, vb0, acc[dt], 0, 0, 0);
            acc[dt] = __builtin_amdgcn_mfma_f32_16x16x32_bf16(pa1, vb1, acc[dt], 0, 0, 0);
        }
    }

    // reduce den over the 16-lane key dimension
#pragma unroll
    for (int r = 0; r < 4; ++r)
#pragma unroll
        for (int mm = 1; mm < 16; mm <<= 1)
            den[r] += __shfl_xor(den[r], mm, 64);

    // store bf16 partial acc + f32 partial den
    ushort* pa_out = pacc + ((size_t)ks * 8 + h) * 4096 * 64;
#pragma unroll
    for (int dt = 0; dt < 4; ++dt)
#pragma unroll
        for (int r = 0; r < 4; ++r) {
            int qi = q0w + lk * 4 + r;
            __builtin_nontemporal_store(f2bf(acc[dt][r]), pa_out + (size_t)qi * 64 + dt * 16 + la);
        }
    if (la == 0) {
        float* pd = pden + ((size_t)ks * 8 + h) * 4096;
#pragma unroll
        for (int r = 0; r < 4; ++r)
            pd[q0w + lk * 4 + r] = den[r];
    }
}

// ---------------- kernel 3: combine bf16 partials + epilogue ----------------
__global__ __launch_bounds__(256) void combine_kernel(const float* __restrict__ x,
                                                      const ushort* __restrict__ pacc,
                                                      const float* __restrict__ pden,
                                                      float* __restrict__ out) {
    int idx = blockIdx.x * 256 + threadIdx.x;   // 524288 total
    int n = idx >> 7, fq = idx & 127;
    int h = fq >> 4;
    int d4 = (fq & 15) * 4;

    float4 o = make_float4(0.f, 0.f, 0.f, 0.f);
    float den = 0.f;
#pragma unroll
    for (int ksp = 0; ksp < 4; ++ksp) {
        const ushort* pa = pacc + (((size_t)ksp * 8 + h) * 4096 + n) * 64 + d4;
        ushort4 p = *reinterpret_cast<const ushort4*>(pa);
        o.x += bf2f(p.x); o.y += bf2f(p.y); o.z += bf2f(p.z); o.w += bf2f(p.w);
        den += pden[((size_t)ksp * 8 + h) * 4096 + n];
    }
    float4 xv = *reinterpret_cast<const float4*>(x + (size_t)n * 512 + fq * 4);
    float inv = 1.f / den;
    float4 r;
    r.x = o.x * inv + xv.x;
    r.y = o.y * inv + xv.y;
    r.z = o.z * inv + xv.z;
    r.w = o.w * inv + xv.w;
    r.x = (r.x > 0.f) ? r.x : (__expf(r.x) - 1.f);
    r.y = (r.y > 0.f) ? r.y : (__expf(r.y) - 1.f);
    r.z = (r.z > 0.f) ? r.z : (__expf(r.z) - 1.f);
    r.w = (r.w > 0.f) ? r.w : (__expf(r.w) - 1.f);
    *reinterpret_cast<float4*>(out + (size_t)n * 512 + fq * 4) = r;
}

extern "C" void kernel_launch(void* const* d_in, const int* in_sizes, int n_in,
                              void* d_out, int out_size, void* d_ws, size_t ws_size,
                              hipStream_t stream) {
    const float* x  = (const float*)d_in[0];
    const float* wq = (const float*)d_in[1];
    const float* wk = (const float*)d_in[2];
    const float* wv = (const float*)d_in[3];
    const int*   adj = (const int*)d_in[4];
    float* out = (float*)d_out;
    ushort* ws = (ushort*)d_ws;
    ushort* pacc = ws + PACC_OFF;
    float* pden = (float*)(ws + PDEN_USHORT_OFF);
    unsigned int* pk = (unsigned int*)(ws + PK_USHORT_OFF);

    cvt_kernel<<<2816, 256, 0, stream>>>(x, wq, wk, wv, ws);
    packqkv_kernel<<<9728, 256, 0, stream>>>(adj, pk, ws);
    attn_kernel<<<2048, 256, 0, stream>>>(pk, ws, pacc, pden);
    combine_kernel<<<2048, 256, 0, stream>>>(x, pacc, pden, out);
}